// Round 4
// baseline (387.136 us; speedup 1.0000x reference)
//
#include <hip/hip_runtime.h>
#include <math.h>

#define B_ROWS 65536
#define N_COLS 512
#define EPS 1e-8f

// R3 post-mortem: occupancy 25->61% changed nothing (110->120us); three
// different kernels all hit ~110-145us at only ~2 TB/s effective. Not
// occupancy-bound: the 2KB-read/256KB-jump pattern (one residue per block)
// caps per-CU memory parallelism. R2's linear scratch traffic hit 2.7 TB/s
// on the same chip => contiguity is the lever.
//
// R4: multi-residue blocks. 8 residue slabs in LDS (16 KB); block owns rows
// 128k + 8g + d (d=0..7) => 16 KB contiguous per array per k-step, and the
// 16 blocks of a k-group collectively cover a contiguous 256 KB region.
// Slab accumulation via LDS atomicAdd with wave-rotated row order and a
// permuted layout pi(j)=(j&3)*128+(j>>2) (2 lanes/bank, conflict-free).
//
// Grid: 512 blocks x 512 threads (8 waves). Block = (q = bid>>4, g = bid&15):
//   residues 8g..8g+7, k in [16q, 16q+16); wave w: k = 16q + 2w + kk.
// Per wave: 2 k-steps x 8 rows = 16 rows.
//
// ws layout (floats): sim[65536] | colsum[128*512] | colTot[512] | acc[16]
// Algebraic eliminations (sim<1, toe<1 => max(log,EPS)==EPS):
//   second = EPS*sum(sim); third = EPS/N * sum_s <colsum_s, simslab_s>.

__global__ __launch_bounds__(512, 4) void k_main(
        const float* __restrict__ A, const float* __restrict__ Bn,
        float* __restrict__ sim, float* __restrict__ colsum,
        float* __restrict__ acc) {
    __shared__ float slab[8 * 512];   // 16 KB, permuted column layout
    __shared__ float sred[16];
    const int t    = threadIdx.x;
    const int lane = t & 63;
    const int w    = t >> 6;                 // 0..7
    const int g    = blockIdx.x & 15;        // residue group: 8g..8g+7
    const int q    = blockIdx.x >> 4;        // 0..31 k-group

    for (int i = t; i < 8 * 512; i += 512) slab[i] = 0.f;
    __syncthreads();

    float accLog = 0.f, accSim = 0.f;

#pragma unroll 1
    for (int kk = 0; kk < 2; ++kk) {
        const int k = q * 16 + w * 2 + kk;
        const int rowIdx0 = 128 * k + 8 * g;
        const size_t rowbase = (size_t)rowIdx0 * N_COLS;

#pragma unroll 1
        for (int jb = 0; jb < 8; jb += 4) {
            // ---- batch of 4 rows: issue all 16 loads first ----
            int dd[4];
            float4 A0[4], A1[4], B0[4], B1[4];
#pragma unroll
            for (int i = 0; i < 4; ++i) {
                const int d = ((jb + i) + w) & 7;   // wave-rotated row order
                dd[i] = d;
                const float* ap = A  + rowbase + d * N_COLS + lane * 4;
                const float* bp = Bn + rowbase + d * N_COLS + lane * 4;
                A0[i] = *(const float4*)ap;
                A1[i] = *(const float4*)(ap + 256);
                B0[i] = *(const float4*)bp;
                B1[i] = *(const float4*)(bp + 256);
            }
#pragma unroll
            for (int i = 0; i < 4; ++i) {
                const float av[8] = {A0[i].x, A0[i].y, A0[i].z, A0[i].w,
                                     A1[i].x, A1[i].y, A1[i].z, A1[i].w};
                const float bv[8] = {B0[i].x, B0[i].y, B0[i].z, B0[i].w,
                                     B1[i].x, B1[i].y, B1[i].z, B1[i].w};
                float ea[8];
                float sA = 0.f, sB = 0.f, dp = 0.f;
#pragma unroll
                for (int c = 0; c < 8; ++c) {
                    float e = __expf(av[c]);
                    float f = __expf(bv[c]);
                    ea[c] = e;
                    sA += e; sB += f; dp += e * f;
                }
#pragma unroll
                for (int m = 32; m >= 1; m >>= 1) {
                    sA += __shfl_xor(sA, m, 64);
                    sB += __shfl_xor(sB, m, 64);
                    dp += __shfl_xor(dp, m, 64);
                }
                const float inv = 1.f / sA;
                float* sl = slab + dd[i] * 512;
                // permuted layout: column 4l+c -> c*128+l ; 256+4l+c -> c*128+64+l
#pragma unroll
                for (int c = 0; c < 4; ++c)
                    atomicAdd(&sl[c * 128 + lane], ea[c] * inv);
#pragma unroll
                for (int c = 0; c < 4; ++c)
                    atomicAdd(&sl[c * 128 + 64 + lane], ea[4 + c] * inv);
                if (lane == 0) {
                    float sv = dp * inv * (1.f / sB);
                    sim[rowIdx0 + dd[i]] = sv;
                    accLog += fmaxf(__logf(sv), -100.f);
                    accSim += fmaxf(sv, EPS);
                }
            }
        }
    }

    if (lane == 0) { sred[w] = accLog; sred[8 + w] = accSim; }
    __syncthreads();

    // unpermute: slab position p = c*128+m : m<64 -> col 4m+c ; else 256+4(m-64)+c
    {
        const int c = t >> 7, m = t & 127;
        const int j = (m < 64) ? (m * 4 + c) : (256 + (m - 64) * 4 + c);
#pragma unroll
        for (int d = 0; d < 8; ++d)
            atomicAdd(&colsum[(size_t)(8 * g + d) * 512 + j], slab[d * 512 + t]);
    }
    if (t == 0) {
        float l = 0.f, s2 = 0.f;
#pragma unroll
        for (int i = 0; i < 8; ++i) { l += sred[i]; s2 += sred[8 + i]; }
        atomicAdd(&acc[0], l);
        atomicAdd(&acc[1], s2);
    }
}

// 64 blocks x 512 threads: column totals (for entropy) + toe dot-product.
__global__ __launch_bounds__(512) void k_red(
        const float* __restrict__ colsum, const float* __restrict__ sim,
        float* __restrict__ colTot, float* __restrict__ acc) {
    __shared__ float red[8];
    const int t = threadIdx.x, lane = t & 63, w = t >> 6;
    const int s0 = blockIdx.x * 2;
    float tot = 0.f, toe = 0.f;
#pragma unroll
    for (int k = 0; k < 2; ++k) {
        int idx = (s0 + k) * 512 + t;
        float c = colsum[idx];
        tot += c;
        toe += c * sim[idx];
    }
    atomicAdd(&colTot[t], tot);
#pragma unroll
    for (int m = 32; m >= 1; m >>= 1) toe += __shfl_xor(toe, m, 64);
    if (lane == 0) red[w] = toe;
    __syncthreads();
    if (t == 0) {
        float tt = red[0] + red[1] + red[2] + red[3]
                 + red[4] + red[5] + red[6] + red[7];
        atomicAdd(&acc[2], tt);
    }
}

__global__ __launch_bounds__(512) void k_fin(
        const float* __restrict__ colTot, const float* __restrict__ acc,
        float* __restrict__ out) {
    __shared__ float red[8];
    const int t = threadIdx.x, lane = t & 63, w = t >> 6;
    float p   = fmaxf(colTot[t] * (1.f / B_ROWS), EPS);
    float ent = -p * __logf(p);
#pragma unroll
    for (int m = 32; m >= 1; m >>= 1) ent += __shfl_xor(ent, m, 64);
    if (lane == 0) red[w] = ent;
    __syncthreads();
    if (t == 0) {
        float entropy = red[0] + red[1] + red[2] + red[3]
                      + red[4] + red[5] + red[6] + red[7];
        float consistency = -acc[0] * (1.f / B_ROWS);
        float second      = acc[1] * EPS;
        float third       = acc[2] * EPS * (1.f / N_COLS);
        float third_weight = 0.5f / sqrtf((float)N_COLS);
        float diff_weight  = 0.25f / (float)N_COLS;
        out[0] = consistency - 2.0f * entropy + diff_weight * second
                 - third_weight * third;
        out[1] = consistency;
        out[2] = entropy;
        out[3] = second;
        out[4] = third;
    }
}

extern "C" void kernel_launch(void* const* d_in, const int* in_sizes, int n_in,
                              void* d_out, int out_size, void* d_ws, size_t ws_size,
                              hipStream_t stream) {
    const float* anchors   = (const float*)d_in[0];
    const float* neighbors = (const float*)d_in[1];
    float* out = (float*)d_out;

    float* sim    = (float*)d_ws;            // 65536 f32
    float* colsum = sim + B_ROWS;            // 128*512 f32 (256 KB)
    float* colTot = colsum + 128 * 512;      // 512 f32
    float* acc    = colTot + 512;            // 16 f32

    hipMemsetAsync(colsum, 0, (128 * 512 + 512 + 16) * sizeof(float), stream);

    k_main<<<dim3(512), dim3(512), 0, stream>>>(
        anchors, neighbors, sim, colsum, acc);
    k_red<<<dim3(64), dim3(512), 0, stream>>>(colsum, sim, colTot, acc);
    k_fin<<<dim3(1), dim3(512), 0, stream>>>(colTot, acc, out);
}

// Round 5
// 299.139 us; speedup vs baseline: 1.2942x; 1.2942x over previous
//
#include <hip/hip_runtime.h>
#include <math.h>

#define B_ROWS 65536
#define N_COLS 512
#define EPS 1e-8f
#define GRID1 2048   // 2048 blocks x 4 waves x 8 rows = 65536 rows

// R4 post-mortem: contiguity made it worse; R2's "accidental" win (4.3 TB/s
// demand incl. scratch) shows the chip delivers when memory issue is
// CONTINUOUS. All our variants burst-load then hard-wait then compute ->
// memory duty ~35% (convoy). R5: per-wave async pipeline via
// global_load_lds (width 16) into 4 wave-private LDS slots, 3 stages in
// flight, counted s_waitcnt vmcnt(N) (never 0 mid-loop), no barriers in the
// loop. DMA-to-LDS costs no VGPRs -> no spill risk.
//
// ws layout (floats): sim[65536] | colsum[128*512] | colTot[512] | acc[16]
// Algebraic eliminations (sim<1, toe<1 => max(log,EPS)==EPS):
//   second = EPS*sum(sim); third = EPS/N * sum_s <colsum_s, simslab_s>.

typedef const __attribute__((address_space(1))) void glb_v;
typedef __attribute__((address_space(3))) void lds_v;

// one call stages 64 lanes x 16 B = 1 KB; lane i -> lds base + 16*i (linear)
#define GLLDS(g, l) \
    __builtin_amdgcn_global_load_lds((glb_v*)(g), (lds_v*)(l), 16, 0, 0)
#define WAITVM(n) asm volatile("s_waitcnt vmcnt(" #n ")" ::: "memory")

__global__ __launch_bounds__(256) void k_main(
        const float* __restrict__ A, const float* __restrict__ Bn,
        float* __restrict__ sim, float* __restrict__ colsum,
        float* __restrict__ acc) {
    __shared__ float tile[4][4][1024]; // [wave][slot][A 512 | B 512] = 64 KB
    __shared__ float cs[512];
    __shared__ float sred[16];
    const int t    = threadIdx.x;
    const int lane = t & 63;
    const int w    = t >> 6;
    const int s    = blockIdx.x & 127;               // residue
    const int kb   = (blockIdx.x >> 7) * 32 + w * 8; // row-multiplier base

    cs[t] = 0.f; cs[t + 256] = 0.f;   // barrier before use is after the loop

    float cacc[8];
#pragma unroll
    for (int k = 0; k < 8; ++k) cacc[k] = 0.f;
    float accLog = 0.f, accSim = 0.f;

    const size_t rowbase = (size_t)(s + 128 * kb) * N_COLS;
    const float* Ab = A  + rowbase + lane * 4;   // per-lane global src
    const float* Bb = Bn + rowbase + lane * 4;
    const size_t rstride = (size_t)128 * N_COLS;
    float* myt = &tile[w][0][0];                 // wave-private 16 KB

#define STAGE(r) do {                                                   \
        float* sl_ = myt + ((r) & 3) * 1024;                            \
        const float* ga_ = Ab + (size_t)(r) * rstride;                  \
        const float* gb_ = Bb + (size_t)(r) * rstride;                  \
        GLLDS(ga_,       sl_);                                          \
        GLLDS(ga_ + 256, sl_ + 256);                                    \
        GLLDS(gb_,       sl_ + 512);                                    \
        GLLDS(gb_ + 256, sl_ + 768);                                    \
    } while (0)

    STAGE(0); STAGE(1); STAGE(2);   // prologue: 3 stages in flight

#define ROWSTEP(r, VM) do {                                             \
        if ((r) + 3 < 8) STAGE((r) + 3);                                \
        WAITVM(VM);  /* stage r landed; 3 newer stages stay in flight */\
        const float* sl_ = myt + ((r) & 3) * 1024;                      \
        const float4 a0 = *(const float4*)(sl_ + lane * 4);             \
        const float4 a1 = *(const float4*)(sl_ + 256 + lane * 4);       \
        const float4 b0 = *(const float4*)(sl_ + 512 + lane * 4);      \
        const float4 b1 = *(const float4*)(sl_ + 768 + lane * 4);      \
        const float av[8] = {a0.x, a0.y, a0.z, a0.w,                    \
                             a1.x, a1.y, a1.z, a1.w};                   \
        const float bv[8] = {b0.x, b0.y, b0.z, b0.w,                    \
                             b1.x, b1.y, b1.z, b1.w};                   \
        float ea[8];                                                    \
        float sA = 0.f, sB = 0.f, dp = 0.f;                             \
        _Pragma("unroll")                                               \
        for (int c = 0; c < 8; ++c) {                                   \
            float e = __expf(av[c]);                                    \
            float f = __expf(bv[c]);                                    \
            ea[c] = e;                                                  \
            sA += e; sB += f; dp += e * f;                              \
        }                                                               \
        _Pragma("unroll")                                               \
        for (int m = 32; m >= 1; m >>= 1) {                             \
            sA += __shfl_xor(sA, m, 64);                                \
            sB += __shfl_xor(sB, m, 64);                                \
            dp += __shfl_xor(dp, m, 64);                                \
        }                                                               \
        const float inv = 1.f / sA;                                     \
        _Pragma("unroll")                                               \
        for (int c = 0; c < 8; ++c) cacc[c] += ea[c] * inv;             \
        if (lane == 0) {                                                \
            float sv = dp * inv * (1.f / sB);                           \
            sim[s + 128 * (kb + (r))] = sv;                             \
            accLog += fmaxf(__logf(sv), -100.f);                        \
            accSim += fmaxf(sv, EPS);                                   \
        }                                                               \
    } while (0)

    ROWSTEP(0, 12); ROWSTEP(1, 12); ROWSTEP(2, 12); ROWSTEP(3, 12);
    ROWSTEP(4, 12); ROWSTEP(5, 8);  ROWSTEP(6, 4);  ROWSTEP(7, 0);
#undef ROWSTEP
#undef STAGE

    // ---- epilogue: block reduce (all 4 waves share residue s) ----
    if (lane == 0) { sred[w] = accLog; sred[8 + w] = accSim; }
    __syncthreads();
#pragma unroll
    for (int k = 0; k < 4; ++k) atomicAdd(&cs[lane * 4 + k], cacc[k]);
#pragma unroll
    for (int k = 0; k < 4; ++k) atomicAdd(&cs[256 + lane * 4 + k], cacc[4 + k]);
    __syncthreads();

    float* cdst = colsum + (size_t)s * 512;
    atomicAdd(&cdst[t], cs[t]);
    atomicAdd(&cdst[t + 256], cs[t + 256]);
    if (t == 0) atomicAdd(&acc[0], sred[0] + sred[1] + sred[2] + sred[3]);
    if (t == 1) atomicAdd(&acc[1], sred[8] + sred[9] + sred[10] + sred[11]);
}

// 64 blocks x 512 threads: column totals (for entropy) + toe dot-product.
__global__ __launch_bounds__(512) void k_red(
        const float* __restrict__ colsum, const float* __restrict__ sim,
        float* __restrict__ colTot, float* __restrict__ acc) {
    __shared__ float red[8];
    const int t = threadIdx.x, lane = t & 63, w = t >> 6;
    const int s0 = blockIdx.x * 2;
    float tot = 0.f, toe = 0.f;
#pragma unroll
    for (int k = 0; k < 2; ++k) {
        int idx = (s0 + k) * 512 + t;
        float c = colsum[idx];
        tot += c;
        toe += c * sim[idx];
    }
    atomicAdd(&colTot[t], tot);
#pragma unroll
    for (int m = 32; m >= 1; m >>= 1) toe += __shfl_xor(toe, m, 64);
    if (lane == 0) red[w] = toe;
    __syncthreads();
    if (t == 0) {
        float tt = red[0] + red[1] + red[2] + red[3]
                 + red[4] + red[5] + red[6] + red[7];
        atomicAdd(&acc[2], tt);
    }
}

__global__ __launch_bounds__(512) void k_fin(
        const float* __restrict__ colTot, const float* __restrict__ acc,
        float* __restrict__ out) {
    __shared__ float red[8];
    const int t = threadIdx.x, lane = t & 63, w = t >> 6;
    float p   = fmaxf(colTot[t] * (1.f / B_ROWS), EPS);
    float ent = -p * __logf(p);
#pragma unroll
    for (int m = 32; m >= 1; m >>= 1) ent += __shfl_xor(ent, m, 64);
    if (lane == 0) red[w] = ent;
    __syncthreads();
    if (t == 0) {
        float entropy = red[0] + red[1] + red[2] + red[3]
                      + red[4] + red[5] + red[6] + red[7];
        float consistency = -acc[0] * (1.f / B_ROWS);
        float second      = acc[1] * EPS;
        float third       = acc[2] * EPS * (1.f / N_COLS);
        float third_weight = 0.5f / sqrtf((float)N_COLS);
        float diff_weight  = 0.25f / (float)N_COLS;
        out[0] = consistency - 2.0f * entropy + diff_weight * second
                 - third_weight * third;
        out[1] = consistency;
        out[2] = entropy;
        out[3] = second;
        out[4] = third;
    }
}

extern "C" void kernel_launch(void* const* d_in, const int* in_sizes, int n_in,
                              void* d_out, int out_size, void* d_ws, size_t ws_size,
                              hipStream_t stream) {
    const float* anchors   = (const float*)d_in[0];
    const float* neighbors = (const float*)d_in[1];
    float* out = (float*)d_out;

    float* sim    = (float*)d_ws;            // 65536 f32
    float* colsum = sim + B_ROWS;            // 128*512 f32 (256 KB)
    float* colTot = colsum + 128 * 512;      // 512 f32
    float* acc    = colTot + 512;            // 16 f32

    hipMemsetAsync(colsum, 0, (128 * 512 + 512 + 16) * sizeof(float), stream);

    k_main<<<dim3(GRID1), dim3(256), 0, stream>>>(
        anchors, neighbors, sim, colsum, acc);
    k_red<<<dim3(64), dim3(512), 0, stream>>>(colsum, sim, colTot, acc);
    k_fin<<<dim3(1), dim3(512), 0, stream>>>(colTot, acc, out);
}

// Round 6
// 290.450 us; speedup vs baseline: 1.3329x; 1.0299x over previous
//
#include <hip/hip_runtime.h>
#include <math.h>

#define B_ROWS 65536
#define N_COLS 512
#define EPS 1e-8f
#define GRID1 2048   // 2048 blocks x 4 waves = 8192 waves x 8 rows = 65536

// R5 post-mortem: async DMA pipeline with 70+ KB in flight per CU still
// pinned at 120us / ~2.1 TB/s demand. Five variants (occupancy 18-70%,
// MLP 4-16 deep, async, spills) all ~110-145us => limiter is NOT in the CU.
// Invariant across all: the chip-wide instantaneous read FRONT is 8192
// scattered 2KB rows (every wave strides 256KB). The 6.3 TB/s copy ubench
// presents dense contiguous bursts instead.
//
// R6: keep R0's exact compute skeleton (best: 110us) and change ONLY the
// row->wave map: wave g handles rows {g + 8192*r}, so at step r the chip
// reads rows [8192r, 8192r+8192) = one contiguous 16 MB band. Since
// 8192 % 128 == 0, a wave's rows share residue s = g&127, so per-wave
// register cacc accumulation still works; block flushes 4 per-wave slabs.
//
// ws layout (floats): sim[65536] | colsum[128*512] | colTot[512] | acc[16]
// Algebraic eliminations (sim<1, toe<1 => max(log,EPS)==EPS):
//   second = EPS*sum(sim); third = EPS/N * sum_s <colsum_s, simslab_s>.

__global__ __launch_bounds__(256) void k_main(
        const float* __restrict__ A, const float* __restrict__ Bn,
        float* __restrict__ sim, float* __restrict__ colsum,
        float* __restrict__ acc) {
    __shared__ float cs[4][512];   // one slab per wave (residue g&127)
    __shared__ float sred[16];
    const int t    = threadIdx.x;
    const int lane = t & 63;
    const int w    = t >> 6;
    const int g    = blockIdx.x * 4 + w;   // global wave id 0..8191

    float cacc[8];
#pragma unroll
    for (int k = 0; k < 8; ++k) cacc[k] = 0.f;
    float accLog = 0.f, accSim = 0.f;

#pragma unroll
    for (int batch = 0; batch < 2; ++batch) {
        // ---- 4 rows per batch, all 16 loads issued up front (R0 skeleton);
        //      rows stride 8192 => chip-wide front is a contiguous band ----
        int rows[4];
        float4 a0[4], a1[4], b0[4], b1[4];
#pragma unroll
        for (int q = 0; q < 4; ++q) {
            rows[q] = g + 8192 * (batch * 4 + q);
            const float* a = A  + (size_t)rows[q] * N_COLS;
            const float* b = Bn + (size_t)rows[q] * N_COLS;
            a0[q] = *(const float4*)(a + lane * 4);
            a1[q] = *(const float4*)(a + 256 + lane * 4);
            b0[q] = *(const float4*)(b + lane * 4);
            b1[q] = *(const float4*)(b + 256 + lane * 4);
        }
        // ---- exp + per-lane partials (inputs ~N(0,1): no overflow) ----
        float ea[4][8], sa[4], sb[4], dp[4];
#pragma unroll
        for (int q = 0; q < 4; ++q) {
            float av[8] = {a0[q].x, a0[q].y, a0[q].z, a0[q].w,
                           a1[q].x, a1[q].y, a1[q].z, a1[q].w};
            float bv[8] = {b0[q].x, b0[q].y, b0[q].z, b0[q].w,
                           b1[q].x, b1[q].y, b1[q].z, b1[q].w};
            float sA = 0.f, sB = 0.f, d = 0.f;
#pragma unroll
            for (int k = 0; k < 8; ++k) {
                float e = __expf(av[k]);
                float f = __expf(bv[k]);
                ea[q][k] = e;
                sA += e; sB += f; d += e * f;
            }
            sa[q] = sA; sb[q] = sB; dp[q] = d;
        }
        // ---- 12 independent shuffle chains, pipelined ----
#pragma unroll
        for (int m = 32; m >= 1; m >>= 1) {
#pragma unroll
            for (int q = 0; q < 4; ++q) {
                sa[q] += __shfl_xor(sa[q], m, 64);
                sb[q] += __shfl_xor(sb[q], m, 64);
                dp[q] += __shfl_xor(dp[q], m, 64);
            }
        }
        // ---- emit ----
#pragma unroll
        for (int q = 0; q < 4; ++q) {
            float inv_sa = 1.f / sa[q];
#pragma unroll
            for (int k = 0; k < 8; ++k) cacc[k] += ea[q][k] * inv_sa;
            if (lane == 0) {
                float sv = dp[q] * inv_sa * (1.f / sb[q]);
                sim[rows[q]] = sv;
                float lg = __logf(sv);
                accLog += fmaxf(lg, -100.f);
                accSim += fmaxf(sv, EPS);
            }
        }
    }

    // ---- epilogue: per-wave slab write (plain stores, no init needed) ----
    if (lane == 0) { sred[w] = accLog; sred[8 + w] = accSim; }
#pragma unroll
    for (int k = 0; k < 4; ++k) cs[w][lane * 4 + k] = cacc[k];
#pragma unroll
    for (int k = 0; k < 4; ++k) cs[w][256 + lane * 4 + k] = cacc[4 + k];
    __syncthreads();

    // flush 4 slabs to their residues' colsum rows
#pragma unroll
    for (int ww = 0; ww < 4; ++ww) {
        const int sw = (blockIdx.x * 4 + ww) & 127;
        float* cdst = colsum + (size_t)sw * 512;
        atomicAdd(&cdst[t], cs[ww][t]);
        atomicAdd(&cdst[t + 256], cs[ww][t + 256]);
    }
    if (t == 0) atomicAdd(&acc[0], sred[0] + sred[1] + sred[2] + sred[3]);
    if (t == 1) atomicAdd(&acc[1], sred[8] + sred[9] + sred[10] + sred[11]);
}

// 64 blocks x 512 threads: column totals (for entropy) + toe dot-product.
__global__ __launch_bounds__(512) void k_red(
        const float* __restrict__ colsum, const float* __restrict__ sim,
        float* __restrict__ colTot, float* __restrict__ acc) {
    __shared__ float red[8];
    const int t = threadIdx.x, lane = t & 63, w = t >> 6;
    const int s0 = blockIdx.x * 2;
    float tot = 0.f, toe = 0.f;
#pragma unroll
    for (int k = 0; k < 2; ++k) {
        int idx = (s0 + k) * 512 + t;
        float c = colsum[idx];
        tot += c;
        toe += c * sim[idx];
    }
    atomicAdd(&colTot[t], tot);
#pragma unroll
    for (int m = 32; m >= 1; m >>= 1) toe += __shfl_xor(toe, m, 64);
    if (lane == 0) red[w] = toe;
    __syncthreads();
    if (t == 0) {
        float tt = red[0] + red[1] + red[2] + red[3]
                 + red[4] + red[5] + red[6] + red[7];
        atomicAdd(&acc[2], tt);
    }
}

__global__ __launch_bounds__(512) void k_fin(
        const float* __restrict__ colTot, const float* __restrict__ acc,
        float* __restrict__ out) {
    __shared__ float red[8];
    const int t = threadIdx.x, lane = t & 63, w = t >> 6;
    float p   = fmaxf(colTot[t] * (1.f / B_ROWS), EPS);
    float ent = -p * __logf(p);
#pragma unroll
    for (int m = 32; m >= 1; m >>= 1) ent += __shfl_xor(ent, m, 64);
    if (lane == 0) red[w] = ent;
    __syncthreads();
    if (t == 0) {
        float entropy = red[0] + red[1] + red[2] + red[3]
                      + red[4] + red[5] + red[6] + red[7];
        float consistency = -acc[0] * (1.f / B_ROWS);
        float second      = acc[1] * EPS;
        float third       = acc[2] * EPS * (1.f / N_COLS);
        float third_weight = 0.5f / sqrtf((float)N_COLS);
        float diff_weight  = 0.25f / (float)N_COLS;
        out[0] = consistency - 2.0f * entropy + diff_weight * second
                 - third_weight * third;
        out[1] = consistency;
        out[2] = entropy;
        out[3] = second;
        out[4] = third;
    }
}

extern "C" void kernel_launch(void* const* d_in, const int* in_sizes, int n_in,
                              void* d_out, int out_size, void* d_ws, size_t ws_size,
                              hipStream_t stream) {
    const float* anchors   = (const float*)d_in[0];
    const float* neighbors = (const float*)d_in[1];
    float* out = (float*)d_out;

    float* sim    = (float*)d_ws;            // 65536 f32
    float* colsum = sim + B_ROWS;            // 128*512 f32 (256 KB)
    float* colTot = colsum + 128 * 512;      // 512 f32
    float* acc    = colTot + 512;            // 16 f32

    hipMemsetAsync(colsum, 0, (128 * 512 + 512 + 16) * sizeof(float), stream);

    k_main<<<dim3(GRID1), dim3(256), 0, stream>>>(
        anchors, neighbors, sim, colsum, acc);
    k_red<<<dim3(64), dim3(512), 0, stream>>>(colsum, sim, colTot, acc);
    k_fin<<<dim3(1), dim3(512), 0, stream>>>(colTot, acc, out);
}